// Round 7
// baseline (5869.350 us; speedup 1.0000x reference)
//
#include <hip/hip_runtime.h>
#include <stdint.h>

typedef unsigned long long u64;
typedef uint32_t u32;

// RTRBM CD-k step. Exact JAX-threefry; f64 reference math with f32 fast path +
// f64 boundary fixups for the sampling GEMMs. Recurrence fused into ONE kernel:
// block = 2 b-columns x 512 h, thread = (h, j); U pre-shuffled into coalesced
// blocked layout UB[r/4][h]; rA in LDS (double2 reads). Accumulation order
// bit-identical to R2-R6 (passing) kernels.
#define NV 1024
#define NH 512
#define TT 128
#define BB 256
#define TBsz (TT*BB)          // 32768
#define HTBsz (NH*TBsz)       // 16777216
#define VTBsz (NV*TBsz)       // 33554432
#define NWV (NV/64)           // 16
#define NWH (NH/64)           // 8
#define QCAP 1048576u
#define DELTA 5e-4
#define BTILE 2

// ---------------- Threefry-2x32 (JAX exact) ----------------
__host__ __device__ inline void tf2x32(uint32_t k0, uint32_t k1,
                                       uint32_t x0, uint32_t x1,
                                       uint32_t& o0, uint32_t& o1) {
  const uint32_t ks2 = k0 ^ k1 ^ 0x1BD11BDAu;
#define ROTL(x,d) (((x)<<(d))|((x)>>(32-(d))))
#define RND(r) { x0 += x1; x1 = ROTL(x1,r); x1 ^= x0; }
  x0 += k0;  x1 += k1;
  RND(13) RND(15) RND(26) RND(6)
  x0 += k1;  x1 += ks2 + 1u;
  RND(17) RND(29) RND(16) RND(24)
  x0 += ks2; x1 += k0 + 2u;
  RND(13) RND(15) RND(26) RND(6)
  x0 += k0;  x1 += k1 + 3u;
  RND(17) RND(29) RND(16) RND(24)
  x0 += k1;  x1 += ks2 + 4u;
  RND(13) RND(15) RND(26) RND(6)
  x0 += ks2; x1 += k0 + 5u;
  o0 = x0; o1 = x1;
#undef RND
#undef ROTL
}

__device__ inline double tf_uniform64(uint32_t k0, uint32_t k1, uint32_t i) {
  uint32_t o0, o1;
  tf2x32(k0, k1, 0u, i, o0, o1);
  uint32_t bits = o0 ^ o1;
  uint32_t fb = (bits >> 9) | 0x3f800000u;
  float f = __uint_as_float(fb) - 1.0f;
  return (double)f;
}

__device__ inline double sigmoid64(double x) { return 1.0 / (1.0 + exp(-x)); }

// ---------------- f32 -> f64 convert ----------------
__global__ __launch_bounds__(256) void kcvt(const float* __restrict__ s,
                                            double* __restrict__ d, int n) {
  int i = blockIdx.x * 256 + threadIdx.x;
  if (i < n) d[i] = (double)s[i];
}

// ---------------- UB[r4*NH + h] = float4(U[h][4r4..4r4+3])  (one-time, 1MB) ----
__global__ __launch_bounds__(256) void kprepU(const float* __restrict__ U,
                                              float4* __restrict__ UB) {
  int i = blockIdx.x * 256 + threadIdx.x;      // NH*NH/4 outputs
  int r4 = i / NH;
  int h  = i % NH;
  const float* __restrict__ p = U + (size_t)h*NH + r4*4;
  UB[i] = make_float4(p[0], p[1], p[2], p[3]);
}

// ---------------- bit-pack v_data: f32 [NV][TBsz] -> u64 [TBsz][NWV] -----------
__global__ __launch_bounds__(256) void kpack_f32(const float* __restrict__ in,
                                                 u64* __restrict__ out) {
  int tb = blockIdx.x * 256 + threadIdx.x;
  for (int w = 0; w < NWV; ++w) {
    u64 m = 0;
    #pragma unroll 8
    for (int j = 0; j < 64; ++j)
      m |= (u64)(in[(size_t)(w*64 + j)*TBsz + tb] != 0.0f ? 1 : 0) << j;
    out[(size_t)tb*NWV + w] = m;
  }
}

// ------- WvT[(t*BB+b)*NH + h] = sum_v W[h,v]*vbit  (f64, t-parallel) -----------
// double2 W64 loads (2 v per load), same per-acc FMA order as before.
__global__ __launch_bounds__(256) void kWv(const u64* __restrict__ vb,
                                           const double* __restrict__ W64,
                                           double* __restrict__ WvT) {
  const int HM = 8;
  int t  = blockIdx.x / (NH/HM);
  int h0 = (blockIdx.x % (NH/HM)) * HM;
  int tb = t*BB + threadIdx.x;
  u64 m[NWV];
  #pragma unroll
  for (int w = 0; w < NWV; ++w) m[w] = vb[(size_t)tb*NWV + w];
  double acc[HM];
  #pragma unroll
  for (int i = 0; i < HM; ++i) acc[i] = 0.0;
  const double2* __restrict__ W2 = (const double2*)W64;
  for (int w = 0; w < NWV; ++w) {
    u64 mw = m[w];
    #pragma unroll 8
    for (int j2 = 0; j2 < 32; ++j2) {
      double bd0 = (double)((unsigned)((mw >> (2*j2+0)) & 1ull));
      double bd1 = (double)((unsigned)((mw >> (2*j2+1)) & 1ull));
      int vi = w*32 + j2;               // double2 index base for this pair
      #pragma unroll
      for (int i = 0; i < HM; ++i) {
        double2 wv = W2[(size_t)(h0+i)*(NV/2) + vi];
        acc[i] = fma(bd0, wv.x, acc[i]);
        acc[i] = fma(bd1, wv.y, acc[i]);
      }
    }
  }
  #pragma unroll
  for (int i = 0; i < HM; ++i)
    WvT[(size_t)tb*NH + h0 + i] = acc[i];
}

// ---------------- fused recurrence: block = 2 b-columns, thread = (h, j) --------
// 1024 threads: j = tid>>9 (b-column), h = tid&511. 4 waves/SIMD for latency
// hiding; rA read as double2. Same accumulation order as R2-R6.
__global__ __launch_bounds__(1024) void krecur(const double* __restrict__ WvT,
                                               const float4* __restrict__ UB,
                                               const float* __restrict__ bh,
                                               const float* __restrict__ binit,
                                               double* __restrict__ rT) {
  __shared__ double rA[BTILE][NH];
  const int b0 = blockIdx.x * BTILE;
  const int h = threadIdx.x & (NH-1);
  const int j = threadIdx.x >> 9;        // 0 or 1
  const double bhd = (double)bh[h];
  // t = 0
  {
    double p = sigmoid64(WvT[(size_t)(b0+j)*NH + h] + (double)binit[h]);
    rA[j][h] = p;
    rT[(size_t)(b0+j)*NH + h] = p;
  }
  __syncthreads();
  for (int t = 1; t < TT; ++t) {
    double acc = WvT[((size_t)t*BB + b0 + j)*NH + h];
    double a0=0, a1=0, a2=0, a3=0;
    const double2* __restrict__ rA2 = (const double2*)rA[j];
    #pragma unroll 4
    for (int r = 0; r < NH; r += 4) {
      float4 u4 = UB[(size_t)(r >> 2)*NH + h];
      double2 q01 = rA2[(r>>1)+0];
      double2 q23 = rA2[(r>>1)+1];
      a0 = fma((double)u4.x, q01.x, a0);
      a1 = fma((double)u4.y, q01.y, a1);
      a2 = fma((double)u4.z, q23.x, a2);
      a3 = fma((double)u4.w, q23.y, a3);
    }
    __syncthreads();            // all reads of rA(t-1) complete
    double p = sigmoid64((acc + ((a0+a1)+(a2+a3))) + bhd);
    rA[j][h] = p;
    rT[((size_t)t*BB + b0 + j)*NH + h] = p;
    __syncthreads();            // rA(t) visible
  }
}

// ---------------- transpose rT [t][b][h] f64 -> out_r [h][t][b] f32 -------------
__global__ __launch_bounds__(256) void ktrans(const double* __restrict__ rT,
                                              float* __restrict__ out_r) {
  __shared__ double lds[32][33];
  int t  = blockIdx.x;
  int h0 = blockIdx.y * 32;
  int b0 = blockIdx.z * 32;
  int tx = threadIdx.x & 31;
  int ty = threadIdx.x >> 5;       // 0..7
  #pragma unroll
  for (int i = 0; i < 4; ++i) {
    int row = ty*4 + i;            // b-row
    lds[row][tx] = rT[((size_t)t*BB + b0 + row)*NH + h0 + tx];
  }
  __syncthreads();
  #pragma unroll
  for (int i = 0; i < 4; ++i) {
    int row = ty*4 + i;            // h-row
    out_r[(size_t)(h0+row)*TBsz + (size_t)t*BB + b0 + tx] = (float)lds[tx][row];
  }
}

// ---------------- h1 bits = bernoulli(sk, rT), byte-packed ----------------------
__global__ __launch_bounds__(256) void ksample8(const double* __restrict__ rT,
                                                uint8_t* __restrict__ hbytes,
                                                u32 k0, u32 k1) {
  int i  = blockIdx.x * 256 + threadIdx.x;   // TBsz*64 threads
  int tb = i >> 6;
  int hw = i & 63;                           // byte index
  int t = tb / BB, b = tb % BB;
  const double* __restrict__ rp = rT + ((size_t)t*BB + b)*NH + hw*8;
  unsigned byte = 0;
  #pragma unroll
  for (int j = 0; j < 8; ++j) {
    double p = rp[j];
    double u = tf_uniform64(k0, k1, (u32)((hw*8 + j)*TBsz + tb));
    byte |= (u < p) ? (1u << j) : 0u;
  }
  hbytes[(size_t)tb*(NH/8) + hw] = (uint8_t)byte;
}

// ---------------- v-side fast path (f32): sigmoid(W^T h + bv), bernoulli --------
__global__ __launch_bounds__(256) void kvis32(
    const float* __restrict__ W, const float* __restrict__ bv,
    const u64* __restrict__ hbits, uint8_t* __restrict__ vbytes,
    float* __restrict__ vf, u32* __restrict__ queue, u32* __restrict__ cnt,
    u32 k0, u32 k1) {
  const int VM = 8;
  int t  = blockIdx.x / (NV/VM);
  int v0 = (blockIdx.x % (NV/VM)) * VM;
  int tb = t*BB + threadIdx.x;
  u64 hb[NWH];
  #pragma unroll
  for (int w = 0; w < NWH; ++w) hb[w] = hbits[(size_t)tb*NWH + w];
  float acc[VM];
  #pragma unroll
  for (int i = 0; i < VM; ++i) acc[i] = 0.f;
  for (int w = 0; w < NWH; ++w) {
    u64 mw = hb[w];
    #pragma unroll 8
    for (int j = 0; j < 64; ++j) {
      float bd = (float)((u32)((mw >> j) & 1ull));
      const float* __restrict__ Wp = W + (size_t)(w*64 + j)*NV + v0;
      #pragma unroll
      for (int i = 0; i < VM; ++i) acc[i] = fmaf(bd, Wp[i], acc[i]);
    }
  }
  unsigned byte = 0;
  #pragma unroll
  for (int i = 0; i < VM; ++i) {
    float p = 1.f / (1.f + __expf(-(acc[i] + bv[v0+i])));
    size_t o = (size_t)(v0+i)*TBsz + tb;
    double u = tf_uniform64(k0, k1, (u32)o);
    double diff = (double)p - u;
    unsigned smp = diff > 0.0 ? 1u : 0u;
    if (fabs(diff) < DELTA) {
      u32 s = atomicAdd(cnt, 1u);
      if (s < QCAP) queue[s] = (u32)o;
    }
    byte |= smp << i;
    if (vf) vf[o] = (float)smp;
  }
  if (vbytes) vbytes[(size_t)tb*(NV/8) + (v0 >> 3)] = (uint8_t)byte;
}

// ---------------- v-side exact fixup (f64) --------------------------------------
__global__ __launch_bounds__(256) void kvis_fix(
    const float* __restrict__ W, const float* __restrict__ bv,
    const u64* __restrict__ hbits, u64* __restrict__ fixbits,
    float* __restrict__ vf, const u32* __restrict__ queue,
    const u32* __restrict__ cnt, u32 k0, u32 k1) {
  u32 n = *cnt; if (n > QCAP) n = QCAP;
  for (u32 q = blockIdx.x*256 + threadIdx.x; q < n; q += gridDim.x*256) {
    u32 o = queue[q];
    u32 v = o / TBsz, tb = o % TBsz;
    double a0=0, a1=0, a2=0, a3=0;
    for (int w = 0; w < NWH; ++w) {
      u64 mw = hbits[(size_t)tb*NWH + w];
      for (int j = 0; j < 64; j += 4) {
        if ((mw >> (j+0)) & 1ull) a0 += (double)W[(size_t)(w*64+j+0)*NV + v];
        if ((mw >> (j+1)) & 1ull) a1 += (double)W[(size_t)(w*64+j+1)*NV + v];
        if ((mw >> (j+2)) & 1ull) a2 += (double)W[(size_t)(w*64+j+2)*NV + v];
        if ((mw >> (j+3)) & 1ull) a3 += (double)W[(size_t)(w*64+j+3)*NV + v];
      }
    }
    double p = sigmoid64(((a0+a1)+(a2+a3)) + (double)bv[v]);
    double u = tf_uniform64(k0, k1, o);
    unsigned smp = (u < p) ? 1u : 0u;
    if (vf) vf[o] = (float)smp;
    if (fixbits) {
      size_t wi = (size_t)tb*NWV + (v >> 6);
      unsigned bit = v & 63u;
      unsigned cur = (unsigned)((fixbits[wi] >> bit) & 1ull);
      if (cur != smp) atomicXor(&fixbits[wi], 1ull << bit);
    }
  }
}

// ---------------- h-side fast path (f32), float4 W loads ------------------------
__global__ __launch_bounds__(256) void khid32(
    const u64* __restrict__ vbits, const float* __restrict__ W,
    const float* __restrict__ U, const float* __restrict__ bh,
    const float* __restrict__ binit, const float* __restrict__ r32,
    uint8_t* __restrict__ hbytes, u32* __restrict__ queue,
    u32* __restrict__ cnt, u32 k0, u32 k1) {
  const int HM = 8;
  int t  = blockIdx.x / (NH/HM);
  int h0 = (blockIdx.x % (NH/HM)) * HM;
  int tb = t*BB + threadIdx.x;
  u64 m[NWV];
  #pragma unroll
  for (int w = 0; w < NWV; ++w) m[w] = vbits[(size_t)tb*NWV + w];
  float acc[HM];
  #pragma unroll
  for (int i = 0; i < HM; ++i) acc[i] = 0.f;
  const float4* __restrict__ W4 = (const float4*)W;
  for (int w = 0; w < NWV; ++w) {
    u64 mw = m[w];
    #pragma unroll 4
    for (int j4 = 0; j4 < 16; ++j4) {
      float bd0 = (float)((u32)((mw >> (4*j4+0)) & 1ull));
      float bd1 = (float)((u32)((mw >> (4*j4+1)) & 1ull));
      float bd2 = (float)((u32)((mw >> (4*j4+2)) & 1ull));
      float bd3 = (float)((u32)((mw >> (4*j4+3)) & 1ull));
      int vi = w*16 + j4;                 // float4 index base
      #pragma unroll
      for (int i = 0; i < HM; ++i) {
        float4 wv = W4[(size_t)(h0+i)*(NV/4) + vi];
        acc[i] = fmaf(bd0, wv.x, acc[i]);
        acc[i] = fmaf(bd1, wv.y, acc[i]);
        acc[i] = fmaf(bd2, wv.z, acc[i]);
        acc[i] = fmaf(bd3, wv.w, acc[i]);
      }
    }
  }
  if (t > 0) {
    const float* __restrict__ rp = r32 + (size_t)(t-1)*BB + threadIdx.x;
    #pragma unroll 4
    for (int r = 0; r < NH; ++r) {
      float rv = rp[(size_t)r*TBsz];
      #pragma unroll
      for (int i = 0; i < HM; ++i)
        acc[i] = fmaf(U[(size_t)(h0+i)*NH + r], rv, acc[i]);
    }
    #pragma unroll
    for (int i = 0; i < HM; ++i) acc[i] += bh[h0+i];
  } else {
    #pragma unroll
    for (int i = 0; i < HM; ++i) acc[i] += binit[h0+i];
  }
  unsigned byte = 0;
  #pragma unroll
  for (int i = 0; i < HM; ++i) {
    float p = 1.f / (1.f + __expf(-acc[i]));
    size_t o = (size_t)(h0+i)*TBsz + tb;
    double u = tf_uniform64(k0, k1, (u32)o);
    double diff = (double)p - u;
    unsigned smp = diff > 0.0 ? 1u : 0u;
    if (fabs(diff) < DELTA) {
      u32 s = atomicAdd(cnt, 1u);
      if (s < QCAP) queue[s] = (u32)o;
    }
    byte |= smp << i;
  }
  hbytes[(size_t)tb*(NH/8) + (h0 >> 3)] = (uint8_t)byte;
}

// ---------------- h-side exact fixup (f64) --------------------------------------
__global__ __launch_bounds__(256) void khid_fix(
    const u64* __restrict__ vbits, const float* __restrict__ W,
    const double* __restrict__ U64, const float* __restrict__ bh,
    const float* __restrict__ binit, const double* __restrict__ rT,
    u64* __restrict__ fixbits, const u32* __restrict__ queue,
    const u32* __restrict__ cnt, u32 k0, u32 k1) {
  u32 n = *cnt; if (n > QCAP) n = QCAP;
  for (u32 q = blockIdx.x*256 + threadIdx.x; q < n; q += gridDim.x*256) {
    u32 o = queue[q];
    u32 h = o / TBsz, tb = o % TBsz;
    u32 t = tb / BB, b = tb % BB;
    double a0=0, a1=0, a2=0, a3=0;
    for (int w = 0; w < NWV; ++w) {
      u64 mw = vbits[(size_t)tb*NWV + w];
      for (int j = 0; j < 64; j += 4) {
        if ((mw >> (j+0)) & 1ull) a0 += (double)W[(size_t)h*NV + w*64+j+0];
        if ((mw >> (j+1)) & 1ull) a1 += (double)W[(size_t)h*NV + w*64+j+1];
        if ((mw >> (j+2)) & 1ull) a2 += (double)W[(size_t)h*NV + w*64+j+2];
        if ((mw >> (j+3)) & 1ull) a3 += (double)W[(size_t)h*NV + w*64+j+3];
      }
    }
    double logit = (a0+a1) + (a2+a3);
    if (t > 0) {
      const double* __restrict__ rp = rT + ((size_t)(t-1)*BB + b)*NH;
      const double* __restrict__ Ur = U64 + (size_t)h*NH;
      double u0=0, u1=0, u2=0, u3=0;
      for (int r = 0; r < NH; r += 4) {
        u0 = fma(Ur[r+0], rp[r+0], u0);
        u1 = fma(Ur[r+1], rp[r+1], u1);
        u2 = fma(Ur[r+2], rp[r+2], u2);
        u3 = fma(Ur[r+3], rp[r+3], u3);
      }
      logit = (logit + ((u0+u1)+(u2+u3))) + (double)bh[h];
    } else {
      logit += (double)binit[h];
    }
    double p = sigmoid64(logit);
    double u = tf_uniform64(k0, k1, o);
    unsigned smp = (u < p) ? 1u : 0u;
    size_t wi = (size_t)tb*NWH + (h >> 6);
    unsigned bit = h & 63u;
    unsigned cur = (unsigned)((fixbits[wi] >> bit) & 1ull);
    if (cur != smp) atomicXor(&fixbits[wi], 1ull << bit);
  }
}

extern "C" void kernel_launch(void* const* d_in, const int* in_sizes, int n_in,
                              void* d_out, int out_size, void* d_ws, size_t ws_size,
                              hipStream_t stream) {
  const float* vd    = (const float*)d_in[0];
  const float* W     = (const float*)d_in[1];
  const float* U     = (const float*)d_in[2];
  const float* bh    = (const float*)d_in[3];
  const float* binit = (const float*)d_in[4];
  const float* bv    = (const float*)d_in[5];

  float* out_v = (float*)d_out;            // (V,T,B) final samples (written last)
  float* out_r = (float*)d_out + VTBsz;    // (H,T,B) r_data f32
  // WvT (f64, 134.2MB) aliases out_v; dead before final kvis32 writes out_v.
  double* WvT = (double*)d_out;

  // ws layout (~165 MB)
  char* w = (char*)d_ws;
  double* rT    = (double*)w;  w += (size_t)HTBsz*8;        // 134.2 MB, [t][b][h]
  u64* vdbits   = (u64*)w;     w += (size_t)TBsz*NWV*8;     // 4 MB
  u64* v1bits   = (u64*)w;     w += (size_t)TBsz*NWV*8;     // 4 MB
  u64* h1bits   = (u64*)w;     w += (size_t)TBsz*NWH*8;     // 2 MB
  u64* h2bits   = (u64*)w;     w += (size_t)TBsz*NWH*8;     // 2 MB
  double* W64   = (double*)w;  w += (size_t)NH*NV*8;        // 4 MB
  double* U64   = (double*)w;  w += (size_t)NH*NH*8;        // 2 MB
  float4* UB    = (float4*)w;  w += (size_t)NH*NH*4;        // 1 MB (blocked U)
  u32* q0       = (u32*)w;     w += (size_t)QCAP*4;         // 4 MB
  u32* q1       = (u32*)w;     w += (size_t)QCAP*4;         // 4 MB
  u32* q2       = (u32*)w;     w += (size_t)QCAP*4;         // 4 MB
  u32* cnt      = (u32*)w;     w += 256;
  (void)ws_size; (void)in_sizes; (void)n_in; (void)out_size;

  // host-side key derivation (jax.random.key(42), partitionable threefry splits)
  uint32_t ka0,ka1, sk0,sk1;
  tf2x32(0u,42u, 0u,0u, ka0,ka1);
  tf2x32(0u,42u, 0u,1u, sk0,sk1);
  uint32_t kb0,kb1, k10,k11, k20,k21;
  tf2x32(ka0,ka1, 0u,0u, kb0,kb1);
  tf2x32(ka0,ka1, 0u,1u, k10,k11);
  tf2x32(ka0,ka1, 0u,2u, k20,k21);
  uint32_t kc0,kc1, kf0,kf1;
  tf2x32(kb0,kb1, 0u,0u, kc0,kc1);
  tf2x32(kb0,kb1, 0u,1u, kf0,kf1);

  hipMemsetAsync(cnt, 0, 3*sizeof(u32), stream);

  // 0) f64 copies of W,U; blocked U; pack v_data bits
  kcvt<<<(NH*NV+255)/256, 256, 0, stream>>>(W, W64, NH*NV);
  kcvt<<<(NH*NH+255)/256, 256, 0, stream>>>(U, U64, NH*NH);
  kprepU<<<(NH*NH/4)/256, 256, 0, stream>>>(U, UB);
  kpack_f32<<<TBsz/256, 256, 0, stream>>>(vd, vdbits);

  // 1) WvT = (W @ v_data)^T  (f64, [t][b][h])
  kWv<<<TT*(NH/8), 256, 0, stream>>>(vdbits, W64, WvT);

  // 2) fused mean-field recurrence (ONE launch; per-b independence)
  krecur<<<BB/BTILE, NH*BTILE, 0, stream>>>(WvT, UB, bh, binit, rT);

  // 2b) out_r = f32 transpose of rT
  ktrans<<<dim3(TT, NH/32, BB/32), 256, 0, stream>>>(rT, out_r);

  // 3) h1 = bernoulli(sk, r_data)  [exact f64, byte-packed]
  ksample8<<<(TBsz*64)/256, 256, 0, stream>>>(rT, (uint8_t*)h1bits, sk0, sk1);

  // 4) v1 = bernoulli(k1, sigmoid(W^T h1 + bv)) : f32 fast + f64 fix
  kvis32<<<TT*(NV/8), 256, 0, stream>>>(W, bv, h1bits, (uint8_t*)v1bits, nullptr,
                                        q0, cnt+0, k10, k11);
  kvis_fix<<<128, 256, 0, stream>>>(W, bv, h1bits, v1bits, nullptr,
                                    q0, cnt+0, k10, k11);

  // 5) h2 = bernoulli(k2, sigmoid(W v1 + U r_lag + bias)) : f32 fast + f64 fix
  khid32<<<TT*(NH/8), 256, 0, stream>>>(v1bits, W, U, bh, binit, out_r,
                                        (uint8_t*)h2bits, q1, cnt+1, k20, k21);
  khid_fix<<<128, 256, 0, stream>>>(v1bits, W, U64, bh, binit, rT,
                                    h2bits, q1, cnt+1, k20, k21);

  // 6) v_model = bernoulli(kf, sigmoid(W^T h2 + bv)) -> out_v (f32 0/1)
  kvis32<<<TT*(NV/8), 256, 0, stream>>>(W, bv, h2bits, nullptr, out_v,
                                        q2, cnt+2, kf0, kf1);
  kvis_fix<<<128, 256, 0, stream>>>(W, bv, h2bits, nullptr, out_v,
                                    q2, cnt+2, kf0, kf1);
}

// Round 8
// 4981.876 us; speedup vs baseline: 1.1781x; 1.1781x over previous
//
#include <hip/hip_runtime.h>
#include <stdint.h>

typedef unsigned long long u64;
typedef uint32_t u32;

// RTRBM CD-k step. Exact JAX-threefry; f64 reference math with f32 fast path +
// f64 boundary fixups for the sampling GEMMs. Recurrence: one block per b-column
// (256 blocks), rA double-buffered in LDS (single barrier/step), U in coalesced
// blocked layout UB[r/4][h]. All accumulation orders bit-identical to R2-R7.
#define NV 1024
#define NH 512
#define TT 128
#define BB 256
#define TBsz (TT*BB)          // 32768
#define HTBsz (NH*TBsz)       // 16777216
#define VTBsz (NV*TBsz)       // 33554432
#define NWV (NV/64)           // 16
#define NWH (NH/64)           // 8
#define QCAP 1048576u
#define DELTA 5e-4

// ---------------- Threefry-2x32 (JAX exact) ----------------
__host__ __device__ inline void tf2x32(uint32_t k0, uint32_t k1,
                                       uint32_t x0, uint32_t x1,
                                       uint32_t& o0, uint32_t& o1) {
  const uint32_t ks2 = k0 ^ k1 ^ 0x1BD11BDAu;
#define ROTL(x,d) (((x)<<(d))|((x)>>(32-(d))))
#define RND(r) { x0 += x1; x1 = ROTL(x1,r); x1 ^= x0; }
  x0 += k0;  x1 += k1;
  RND(13) RND(15) RND(26) RND(6)
  x0 += k1;  x1 += ks2 + 1u;
  RND(17) RND(29) RND(16) RND(24)
  x0 += ks2; x1 += k0 + 2u;
  RND(13) RND(15) RND(26) RND(6)
  x0 += k0;  x1 += k1 + 3u;
  RND(17) RND(29) RND(16) RND(24)
  x0 += k1;  x1 += ks2 + 4u;
  RND(13) RND(15) RND(26) RND(6)
  x0 += ks2; x1 += k0 + 5u;
  o0 = x0; o1 = x1;
#undef RND
#undef ROTL
}

__device__ inline double tf_uniform64(uint32_t k0, uint32_t k1, uint32_t i) {
  uint32_t o0, o1;
  tf2x32(k0, k1, 0u, i, o0, o1);
  uint32_t bits = o0 ^ o1;
  uint32_t fb = (bits >> 9) | 0x3f800000u;
  float f = __uint_as_float(fb) - 1.0f;
  return (double)f;
}

__device__ inline double sigmoid64(double x) { return 1.0 / (1.0 + exp(-x)); }

// ---------------- f32 -> f64 convert ----------------
__global__ __launch_bounds__(256) void kcvt(const float* __restrict__ s,
                                            double* __restrict__ d, int n) {
  int i = blockIdx.x * 256 + threadIdx.x;
  if (i < n) d[i] = (double)s[i];
}

// ---------------- UB[r4*NH + h] = float4(U[h][4r4..4r4+3])  (one-time, 1MB) ----
__global__ __launch_bounds__(256) void kprepU(const float* __restrict__ U,
                                              float4* __restrict__ UB) {
  int i = blockIdx.x * 256 + threadIdx.x;      // NH*NH/4 outputs
  int r4 = i / NH;
  int h  = i % NH;
  const float* __restrict__ p = U + (size_t)h*NH + r4*4;
  UB[i] = make_float4(p[0], p[1], p[2], p[3]);
}

// ---------------- UT[r*NH + h] = U[h*NH + r]  (one-time, 1MB) -------------------
__global__ __launch_bounds__(256) void kprepUT(const float* __restrict__ U,
                                               float* __restrict__ UT) {
  int i = blockIdx.x * 256 + threadIdx.x;      // NH*NH
  int r = i / NH;
  int h = i % NH;
  UT[i] = U[(size_t)h*NH + r];
}

// ---------------- bit-pack v_data: f32 [NV][TBsz] -> u64 [TBsz][NWV] -----------
__global__ __launch_bounds__(256) void kpack_f32(const float* __restrict__ in,
                                                 u64* __restrict__ out) {
  int tb = blockIdx.x * 256 + threadIdx.x;
  for (int w = 0; w < NWV; ++w) {
    u64 m = 0;
    #pragma unroll 8
    for (int j = 0; j < 64; ++j)
      m |= (u64)(in[(size_t)(w*64 + j)*TBsz + tb] != 0.0f ? 1 : 0) << j;
    out[(size_t)tb*NWV + w] = m;
  }
}

// ------- WvT[(t*BB+b)*NH + h] = sum_v W[h,v]*vbit  (f64, t-parallel) -----------
__global__ __launch_bounds__(256) void kWv(const u64* __restrict__ vb,
                                           const double* __restrict__ W64,
                                           double* __restrict__ WvT) {
  const int HM = 8;
  int t  = blockIdx.x / (NH/HM);
  int h0 = (blockIdx.x % (NH/HM)) * HM;
  int tb = t*BB + threadIdx.x;
  u64 m[NWV];
  #pragma unroll
  for (int w = 0; w < NWV; ++w) m[w] = vb[(size_t)tb*NWV + w];
  double acc[HM];
  #pragma unroll
  for (int i = 0; i < HM; ++i) acc[i] = 0.0;
  const double2* __restrict__ W2 = (const double2*)W64;
  for (int w = 0; w < NWV; ++w) {
    u64 mw = m[w];
    #pragma unroll 8
    for (int j2 = 0; j2 < 32; ++j2) {
      double bd0 = (double)((unsigned)((mw >> (2*j2+0)) & 1ull));
      double bd1 = (double)((unsigned)((mw >> (2*j2+1)) & 1ull));
      int vi = w*32 + j2;
      #pragma unroll
      for (int i = 0; i < HM; ++i) {
        double2 wv = W2[(size_t)(h0+i)*(NV/2) + vi];
        acc[i] = fma(bd0, wv.x, acc[i]);
        acc[i] = fma(bd1, wv.y, acc[i]);
      }
    }
  }
  #pragma unroll
  for (int i = 0; i < HM; ++i)
    WvT[(size_t)tb*NH + h0 + i] = acc[i];
}

// ---------------- fused recurrence: one block per b-column, dbuf rA -------------
// 256 blocks x 512 threads (thread = h). Single barrier per step. Same per-output
// accumulation order as R2-R7: 4-acc stride-4, ((a0+a1)+(a2+a3)), +bh.
__global__ __launch_bounds__(512) void krecur(const double* __restrict__ WvT,
                                              const float4* __restrict__ UB,
                                              const float* __restrict__ bh,
                                              const float* __restrict__ binit,
                                              double* __restrict__ rT) {
  __shared__ double rA[2][NH];
  const int b = blockIdx.x;
  const int h = threadIdx.x;
  const double bhd = (double)bh[h];
  // t = 0
  double p = sigmoid64(WvT[(size_t)b*NH + h] + (double)binit[h]);
  rA[0][h] = p;
  rT[(size_t)b*NH + h] = p;
  __syncthreads();
  int cur = 0;
  for (int t = 1; t < TT; ++t) {
    double acc = WvT[((size_t)t*BB + b)*NH + h];
    double a0=0, a1=0, a2=0, a3=0;
    const double2* __restrict__ rA2 = (const double2*)rA[cur];
    #pragma unroll 4
    for (int r = 0; r < NH; r += 4) {
      float4 u4 = UB[(size_t)(r >> 2)*NH + h];
      double2 q01 = rA2[(r>>1)+0];
      double2 q23 = rA2[(r>>1)+1];
      a0 = fma((double)u4.x, q01.x, a0);
      a1 = fma((double)u4.y, q01.y, a1);
      a2 = fma((double)u4.z, q23.x, a2);
      a3 = fma((double)u4.w, q23.y, a3);
    }
    p = sigmoid64((acc + ((a0+a1)+(a2+a3))) + bhd);
    rA[cur ^ 1][h] = p;                         // write other buffer
    rT[((size_t)t*BB + b)*NH + h] = p;
    __syncthreads();                            // writes visible; reads of cur done
    cur ^= 1;
  }
}

// ---------------- transpose rT [t][b][h] f64 -> out_r [h][t][b] f32 -------------
__global__ __launch_bounds__(256) void ktrans(const double* __restrict__ rT,
                                              float* __restrict__ out_r) {
  __shared__ double lds[32][33];
  int t  = blockIdx.x;
  int h0 = blockIdx.y * 32;
  int b0 = blockIdx.z * 32;
  int tx = threadIdx.x & 31;
  int ty = threadIdx.x >> 5;       // 0..7
  #pragma unroll
  for (int i = 0; i < 4; ++i) {
    int row = ty*4 + i;            // b-row
    lds[row][tx] = rT[((size_t)t*BB + b0 + row)*NH + h0 + tx];
  }
  __syncthreads();
  #pragma unroll
  for (int i = 0; i < 4; ++i) {
    int row = ty*4 + i;            // h-row
    out_r[(size_t)(h0+row)*TBsz + (size_t)t*BB + b0 + tx] = (float)lds[tx][row];
  }
}

// ---------------- h1 bits = bernoulli(sk, rT), byte-packed ----------------------
__global__ __launch_bounds__(256) void ksample8(const double* __restrict__ rT,
                                                uint8_t* __restrict__ hbytes,
                                                u32 k0, u32 k1) {
  int i  = blockIdx.x * 256 + threadIdx.x;   // TBsz*64 threads
  int tb = i >> 6;
  int hw = i & 63;                           // byte index
  int t = tb / BB, b = tb % BB;
  const double* __restrict__ rp = rT + ((size_t)t*BB + b)*NH + hw*8;
  unsigned byte = 0;
  #pragma unroll
  for (int j = 0; j < 8; ++j) {
    double p = rp[j];
    double u = tf_uniform64(k0, k1, (u32)((hw*8 + j)*TBsz + tb));
    byte |= (u < p) ? (1u << j) : 0u;
  }
  hbytes[(size_t)tb*(NH/8) + hw] = (uint8_t)byte;
}

// ---------------- v-side fast path (f32), VM=16: sigmoid(W^T h + bv) ------------
__global__ __launch_bounds__(256) void kvis32(
    const float* __restrict__ W, const float* __restrict__ bv,
    const u64* __restrict__ hbits, uint8_t* __restrict__ vbytes,
    float* __restrict__ vf, u32* __restrict__ queue, u32* __restrict__ cnt,
    u32 k0, u32 k1) {
  const int VM = 16;
  int t  = blockIdx.x / (NV/VM);
  int v0 = (blockIdx.x % (NV/VM)) * VM;
  int tb = t*BB + threadIdx.x;
  u64 hb[NWH];
  #pragma unroll
  for (int w = 0; w < NWH; ++w) hb[w] = hbits[(size_t)tb*NWH + w];
  float acc[VM];
  #pragma unroll
  for (int i = 0; i < VM; ++i) acc[i] = 0.f;
  for (int w = 0; w < NWH; ++w) {
    u64 mw = hb[w];
    #pragma unroll 4
    for (int j = 0; j < 64; ++j) {
      float bd = (float)((u32)((mw >> j) & 1ull));
      const float4* __restrict__ Wp4 =
          (const float4*)(W + (size_t)(w*64 + j)*NV + v0);
      float4 w0 = Wp4[0], w1 = Wp4[1], w2 = Wp4[2], w3 = Wp4[3];
      acc[ 0] = fmaf(bd, w0.x, acc[ 0]);
      acc[ 1] = fmaf(bd, w0.y, acc[ 1]);
      acc[ 2] = fmaf(bd, w0.z, acc[ 2]);
      acc[ 3] = fmaf(bd, w0.w, acc[ 3]);
      acc[ 4] = fmaf(bd, w1.x, acc[ 4]);
      acc[ 5] = fmaf(bd, w1.y, acc[ 5]);
      acc[ 6] = fmaf(bd, w1.z, acc[ 6]);
      acc[ 7] = fmaf(bd, w1.w, acc[ 7]);
      acc[ 8] = fmaf(bd, w2.x, acc[ 8]);
      acc[ 9] = fmaf(bd, w2.y, acc[ 9]);
      acc[10] = fmaf(bd, w2.z, acc[10]);
      acc[11] = fmaf(bd, w2.w, acc[11]);
      acc[12] = fmaf(bd, w3.x, acc[12]);
      acc[13] = fmaf(bd, w3.y, acc[13]);
      acc[14] = fmaf(bd, w3.z, acc[14]);
      acc[15] = fmaf(bd, w3.w, acc[15]);
    }
  }
  unsigned bits = 0;
  #pragma unroll
  for (int i = 0; i < VM; ++i) {
    float p = 1.f / (1.f + __expf(-(acc[i] + bv[v0+i])));
    size_t o = (size_t)(v0+i)*TBsz + tb;
    double u = tf_uniform64(k0, k1, (u32)o);
    double diff = (double)p - u;
    unsigned smp = diff > 0.0 ? 1u : 0u;
    if (fabs(diff) < DELTA) {
      u32 s = atomicAdd(cnt, 1u);
      if (s < QCAP) queue[s] = (u32)o;
    }
    bits |= smp << i;
    if (vf) vf[o] = (float)smp;
  }
  if (vbytes)
    *(uint16_t*)(vbytes + (size_t)tb*(NV/8) + (v0 >> 3)) = (uint16_t)bits;
}

// ---------------- v-side exact fixup (f64) --------------------------------------
__global__ __launch_bounds__(256) void kvis_fix(
    const float* __restrict__ W, const float* __restrict__ bv,
    const u64* __restrict__ hbits, u64* __restrict__ fixbits,
    float* __restrict__ vf, const u32* __restrict__ queue,
    const u32* __restrict__ cnt, u32 k0, u32 k1) {
  u32 n = *cnt; if (n > QCAP) n = QCAP;
  for (u32 q = blockIdx.x*256 + threadIdx.x; q < n; q += gridDim.x*256) {
    u32 o = queue[q];
    u32 v = o / TBsz, tb = o % TBsz;
    double a0=0, a1=0, a2=0, a3=0;
    for (int w = 0; w < NWH; ++w) {
      u64 mw = hbits[(size_t)tb*NWH + w];
      for (int j = 0; j < 64; j += 4) {
        if ((mw >> (j+0)) & 1ull) a0 += (double)W[(size_t)(w*64+j+0)*NV + v];
        if ((mw >> (j+1)) & 1ull) a1 += (double)W[(size_t)(w*64+j+1)*NV + v];
        if ((mw >> (j+2)) & 1ull) a2 += (double)W[(size_t)(w*64+j+2)*NV + v];
        if ((mw >> (j+3)) & 1ull) a3 += (double)W[(size_t)(w*64+j+3)*NV + v];
      }
    }
    double p = sigmoid64(((a0+a1)+(a2+a3)) + (double)bv[v]);
    double u = tf_uniform64(k0, k1, o);
    unsigned smp = (u < p) ? 1u : 0u;
    if (vf) vf[o] = (float)smp;
    if (fixbits) {
      size_t wi = (size_t)tb*NWV + (v >> 6);
      unsigned bit = v & 63u;
      unsigned cur = (unsigned)((fixbits[wi] >> bit) & 1ull);
      if (cur != smp) atomicXor(&fixbits[wi], 1ull << bit);
    }
  }
}

// ---------------- h-side fast path (f32): float4 W + transposed-U loads ---------
__global__ __launch_bounds__(256) void khid32(
    const u64* __restrict__ vbits, const float* __restrict__ W,
    const float* __restrict__ UT, const float* __restrict__ bh,
    const float* __restrict__ binit, const float* __restrict__ r32,
    uint8_t* __restrict__ hbytes, u32* __restrict__ queue,
    u32* __restrict__ cnt, u32 k0, u32 k1) {
  const int HM = 8;
  int t  = blockIdx.x / (NH/HM);
  int h0 = (blockIdx.x % (NH/HM)) * HM;
  int tb = t*BB + threadIdx.x;
  u64 m[NWV];
  #pragma unroll
  for (int w = 0; w < NWV; ++w) m[w] = vbits[(size_t)tb*NWV + w];
  float acc[HM];
  #pragma unroll
  for (int i = 0; i < HM; ++i) acc[i] = 0.f;
  const float4* __restrict__ W4 = (const float4*)W;
  for (int w = 0; w < NWV; ++w) {
    u64 mw = m[w];
    #pragma unroll 4
    for (int j4 = 0; j4 < 16; ++j4) {
      float bd0 = (float)((u32)((mw >> (4*j4+0)) & 1ull));
      float bd1 = (float)((u32)((mw >> (4*j4+1)) & 1ull));
      float bd2 = (float)((u32)((mw >> (4*j4+2)) & 1ull));
      float bd3 = (float)((u32)((mw >> (4*j4+3)) & 1ull));
      int vi = w*16 + j4;                 // float4 index base
      #pragma unroll
      for (int i = 0; i < HM; ++i) {
        float4 wv = W4[(size_t)(h0+i)*(NV/4) + vi];
        acc[i] = fmaf(bd0, wv.x, acc[i]);
        acc[i] = fmaf(bd1, wv.y, acc[i]);
        acc[i] = fmaf(bd2, wv.z, acc[i]);
        acc[i] = fmaf(bd3, wv.w, acc[i]);
      }
    }
  }
  if (t > 0) {
    const float* __restrict__ rp = r32 + (size_t)(t-1)*BB + threadIdx.x;
    const float4* __restrict__ UT4 = (const float4*)UT;
    #pragma unroll 4
    for (int r = 0; r < NH; ++r) {
      float rv = rp[(size_t)r*TBsz];
      float4 ua = UT4[(size_t)r*(NH/4) + (h0 >> 2) + 0];
      float4 ub = UT4[(size_t)r*(NH/4) + (h0 >> 2) + 1];
      acc[0] = fmaf(ua.x, rv, acc[0]);
      acc[1] = fmaf(ua.y, rv, acc[1]);
      acc[2] = fmaf(ua.z, rv, acc[2]);
      acc[3] = fmaf(ua.w, rv, acc[3]);
      acc[4] = fmaf(ub.x, rv, acc[4]);
      acc[5] = fmaf(ub.y, rv, acc[5]);
      acc[6] = fmaf(ub.z, rv, acc[6]);
      acc[7] = fmaf(ub.w, rv, acc[7]);
    }
    #pragma unroll
    for (int i = 0; i < HM; ++i) acc[i] += bh[h0+i];
  } else {
    #pragma unroll
    for (int i = 0; i < HM; ++i) acc[i] += binit[h0+i];
  }
  unsigned byte = 0;
  #pragma unroll
  for (int i = 0; i < HM; ++i) {
    float p = 1.f / (1.f + __expf(-acc[i]));
    size_t o = (size_t)(h0+i)*TBsz + tb;
    double u = tf_uniform64(k0, k1, (u32)o);
    double diff = (double)p - u;
    unsigned smp = diff > 0.0 ? 1u : 0u;
    if (fabs(diff) < DELTA) {
      u32 s = atomicAdd(cnt, 1u);
      if (s < QCAP) queue[s] = (u32)o;
    }
    byte |= smp << i;
  }
  hbytes[(size_t)tb*(NH/8) + (h0 >> 3)] = (uint8_t)byte;
}

// ---------------- h-side exact fixup (f64) --------------------------------------
__global__ __launch_bounds__(256) void khid_fix(
    const u64* __restrict__ vbits, const float* __restrict__ W,
    const double* __restrict__ U64, const float* __restrict__ bh,
    const float* __restrict__ binit, const double* __restrict__ rT,
    u64* __restrict__ fixbits, const u32* __restrict__ queue,
    const u32* __restrict__ cnt, u32 k0, u32 k1) {
  u32 n = *cnt; if (n > QCAP) n = QCAP;
  for (u32 q = blockIdx.x*256 + threadIdx.x; q < n; q += gridDim.x*256) {
    u32 o = queue[q];
    u32 h = o / TBsz, tb = o % TBsz;
    u32 t = tb / BB, b = tb % BB;
    double a0=0, a1=0, a2=0, a3=0;
    for (int w = 0; w < NWV; ++w) {
      u64 mw = vbits[(size_t)tb*NWV + w];
      for (int j = 0; j < 64; j += 4) {
        if ((mw >> (j+0)) & 1ull) a0 += (double)W[(size_t)h*NV + w*64+j+0];
        if ((mw >> (j+1)) & 1ull) a1 += (double)W[(size_t)h*NV + w*64+j+1];
        if ((mw >> (j+2)) & 1ull) a2 += (double)W[(size_t)h*NV + w*64+j+2];
        if ((mw >> (j+3)) & 1ull) a3 += (double)W[(size_t)h*NV + w*64+j+3];
      }
    }
    double logit = (a0+a1) + (a2+a3);
    if (t > 0) {
      const double* __restrict__ rp = rT + ((size_t)(t-1)*BB + b)*NH;
      const double* __restrict__ Ur = U64 + (size_t)h*NH;
      double u0=0, u1=0, u2=0, u3=0;
      for (int r = 0; r < NH; r += 4) {
        u0 = fma(Ur[r+0], rp[r+0], u0);
        u1 = fma(Ur[r+1], rp[r+1], u1);
        u2 = fma(Ur[r+2], rp[r+2], u2);
        u3 = fma(Ur[r+3], rp[r+3], u3);
      }
      logit = (logit + ((u0+u1)+(u2+u3))) + (double)bh[h];
    } else {
      logit += (double)binit[h];
    }
    double p = sigmoid64(logit);
    double u = tf_uniform64(k0, k1, o);
    unsigned smp = (u < p) ? 1u : 0u;
    size_t wi = (size_t)tb*NWH + (h >> 6);
    unsigned bit = h & 63u;
    unsigned cur = (unsigned)((fixbits[wi] >> bit) & 1ull);
    if (cur != smp) atomicXor(&fixbits[wi], 1ull << bit);
  }
}

extern "C" void kernel_launch(void* const* d_in, const int* in_sizes, int n_in,
                              void* d_out, int out_size, void* d_ws, size_t ws_size,
                              hipStream_t stream) {
  const float* vd    = (const float*)d_in[0];
  const float* W     = (const float*)d_in[1];
  const float* U     = (const float*)d_in[2];
  const float* bh    = (const float*)d_in[3];
  const float* binit = (const float*)d_in[4];
  const float* bv    = (const float*)d_in[5];

  float* out_v = (float*)d_out;            // (V,T,B) final samples (written last)
  float* out_r = (float*)d_out + VTBsz;    // (H,T,B) r_data f32
  // WvT (f64, 134.2MB) aliases out_v; dead before final kvis32 writes out_v.
  double* WvT = (double*)d_out;

  // ws layout (~166 MB)
  char* w = (char*)d_ws;
  double* rT    = (double*)w;  w += (size_t)HTBsz*8;        // 134.2 MB, [t][b][h]
  u64* vdbits   = (u64*)w;     w += (size_t)TBsz*NWV*8;     // 4 MB
  u64* v1bits   = (u64*)w;     w += (size_t)TBsz*NWV*8;     // 4 MB
  u64* h1bits   = (u64*)w;     w += (size_t)TBsz*NWH*8;     // 2 MB
  u64* h2bits   = (u64*)w;     w += (size_t)TBsz*NWH*8;     // 2 MB
  double* W64   = (double*)w;  w += (size_t)NH*NV*8;        // 4 MB
  double* U64   = (double*)w;  w += (size_t)NH*NH*8;        // 2 MB
  float4* UB    = (float4*)w;  w += (size_t)NH*NH*4;        // 1 MB (blocked U)
  float* UT     = (float*)w;   w += (size_t)NH*NH*4;        // 1 MB (transposed U)
  u32* q0       = (u32*)w;     w += (size_t)QCAP*4;         // 4 MB
  u32* q1       = (u32*)w;     w += (size_t)QCAP*4;         // 4 MB
  u32* q2       = (u32*)w;     w += (size_t)QCAP*4;         // 4 MB
  u32* cnt      = (u32*)w;     w += 256;
  (void)ws_size; (void)in_sizes; (void)n_in; (void)out_size;

  // host-side key derivation (jax.random.key(42), partitionable threefry splits)
  uint32_t ka0,ka1, sk0,sk1;
  tf2x32(0u,42u, 0u,0u, ka0,ka1);
  tf2x32(0u,42u, 0u,1u, sk0,sk1);
  uint32_t kb0,kb1, k10,k11, k20,k21;
  tf2x32(ka0,ka1, 0u,0u, kb0,kb1);
  tf2x32(ka0,ka1, 0u,1u, k10,k11);
  tf2x32(ka0,ka1, 0u,2u, k20,k21);
  uint32_t kc0,kc1, kf0,kf1;
  tf2x32(kb0,kb1, 0u,0u, kc0,kc1);
  tf2x32(kb0,kb1, 0u,1u, kf0,kf1);

  hipMemsetAsync(cnt, 0, 3*sizeof(u32), stream);

  // 0) f64 copies of W,U; blocked + transposed U; pack v_data bits
  kcvt<<<(NH*NV+255)/256, 256, 0, stream>>>(W, W64, NH*NV);
  kcvt<<<(NH*NH+255)/256, 256, 0, stream>>>(U, U64, NH*NH);
  kprepU<<<(NH*NH/4)/256, 256, 0, stream>>>(U, UB);
  kprepUT<<<(NH*NH)/256, 256, 0, stream>>>(U, UT);
  kpack_f32<<<TBsz/256, 256, 0, stream>>>(vd, vdbits);

  // 1) WvT = (W @ v_data)^T  (f64, [t][b][h])
  kWv<<<TT*(NH/8), 256, 0, stream>>>(vdbits, W64, WvT);

  // 2) fused mean-field recurrence (ONE launch; 256 blocks; dbuf single barrier)
  krecur<<<BB, NH, 0, stream>>>(WvT, UB, bh, binit, rT);

  // 2b) out_r = f32 transpose of rT
  ktrans<<<dim3(TT, NH/32, BB/32), 256, 0, stream>>>(rT, out_r);

  // 3) h1 = bernoulli(sk, r_data)  [exact f64, byte-packed]
  ksample8<<<(TBsz*64)/256, 256, 0, stream>>>(rT, (uint8_t*)h1bits, sk0, sk1);

  // 4) v1 = bernoulli(k1, sigmoid(W^T h1 + bv)) : f32 fast + f64 fix
  kvis32<<<TT*(NV/16), 256, 0, stream>>>(W, bv, h1bits, (uint8_t*)v1bits, nullptr,
                                         q0, cnt+0, k10, k11);
  kvis_fix<<<128, 256, 0, stream>>>(W, bv, h1bits, v1bits, nullptr,
                                    q0, cnt+0, k10, k11);

  // 5) h2 = bernoulli(k2, sigmoid(W v1 + U r_lag + bias)) : f32 fast + f64 fix
  khid32<<<TT*(NH/8), 256, 0, stream>>>(v1bits, W, UT, bh, binit, out_r,
                                        (uint8_t*)h2bits, q1, cnt+1, k20, k21);
  khid_fix<<<128, 256, 0, stream>>>(v1bits, W, U64, bh, binit, rT,
                                    h2bits, q1, cnt+1, k20, k21);

  // 6) v_model = bernoulli(kf, sigmoid(W^T h2 + bv)) -> out_v (f32 0/1)
  kvis32<<<TT*(NV/16), 256, 0, stream>>>(W, bv, h2bits, nullptr, out_v,
                                         q2, cnt+2, kf0, kf1);
  kvis_fix<<<128, 256, 0, stream>>>(W, bv, h2bits, nullptr, out_v,
                                    q2, cnt+2, kf0, kf1);
}